// Round 5
// baseline (267.189 us; speedup 1.0000x reference)
//
#include <hip/hip_runtime.h>
#include <stdint.h>

typedef __bf16 bf16;
typedef __bf16 bf16x4 __attribute__((ext_vector_type(4)));
typedef __bf16 bf16x8 __attribute__((ext_vector_type(8)));
typedef float f32x4 __attribute__((ext_vector_type(4)));

#define MFMA_16x16x32(a, b, c) __builtin_amdgcn_mfma_f32_16x16x32_bf16((a), (b), (c), 0, 0, 0)

// async global->LDS, 16B per lane. LDS dest must be wave-uniform base + lane*16.
__device__ __forceinline__ void gl_lds16(const bf16* g, bf16* l) {
    __builtin_amdgcn_global_load_lds(
        (const __attribute__((address_space(1))) void*)g,
        (__attribute__((address_space(3))) void*)l, 16, 0, 0);
}

// ---------------------------------------------------------------------------
// prep: blocks [0,2048) = LayerNorm (4 rows each, f32 in, bf16 out, f32 g/b);
//       blocks [2048,2432) = w_in f32->bf16; [2432,2560) = w_out f32->bf16.
// ---------------------------------------------------------------------------
__global__ __launch_bounds__(256) void prep_kernel(const float* __restrict__ x,
                                                   const float* __restrict__ gamma,
                                                   const float* __restrict__ beta,
                                                   const float* __restrict__ w_in,
                                                   const float* __restrict__ w_out,
                                                   bf16* __restrict__ xn,
                                                   bf16* __restrict__ cw_in,
                                                   bf16* __restrict__ cw_out) {
    const int bid = blockIdx.x;
    if (bid < 2048) {
        const int lane = threadIdx.x & 63;
        const int row = (bid << 2) + (threadIdx.x >> 6);
        const size_t base = (size_t)row * 512 + lane * 8;
        const float* xf = x + base;
        float4 a = *(const float4*)xf;
        float4 b = *(const float4*)(xf + 4);
        float f[8] = {a.x, a.y, a.z, a.w, b.x, b.y, b.z, b.w};
        float s = 0.f;
#pragma unroll
        for (int j = 0; j < 8; ++j) s += f[j];
#pragma unroll
        for (int off = 32; off >= 1; off >>= 1) s += __shfl_xor(s, off, 64);
        const float mu = s * (1.0f / 512.0f);
        float vs = 0.f;
#pragma unroll
        for (int j = 0; j < 8; ++j) { float d = f[j] - mu; vs += d * d; }
#pragma unroll
        for (int off = 32; off >= 1; off >>= 1) vs += __shfl_xor(vs, off, 64);
        const float rstd = rsqrtf(vs * (1.0f / 512.0f) + 1e-5f);
        float4 g0 = *(const float4*)(gamma + lane * 8);
        float4 g1 = *(const float4*)(gamma + lane * 8 + 4);
        float4 b0 = *(const float4*)(beta + lane * 8);
        float4 b1 = *(const float4*)(beta + lane * 8 + 4);
        float gg[8] = {g0.x, g0.y, g0.z, g0.w, g1.x, g1.y, g1.z, g1.w};
        float bb[8] = {b0.x, b0.y, b0.z, b0.w, b1.x, b1.y, b1.z, b1.w};
        bf16x8 o;
#pragma unroll
        for (int j = 0; j < 8; ++j)
            o[j] = (bf16)((f[j] - mu) * rstd * gg[j] + bb[j]);
        *(bf16x8*)(xn + base) = o;
    } else {
        const float* src;
        bf16* dst;
        int base;
        if (bid < 2432) { src = w_in;  dst = cw_in;  base = (bid - 2048) * 2048; }
        else            { src = w_out; dst = cw_out; base = (bid - 2432) * 2048; }
        const int i = base + threadIdx.x * 8;
        float4 a = *(const float4*)(src + i);
        float4 b = *(const float4*)(src + i + 4);
        float f[8] = {a.x, a.y, a.z, a.w, b.x, b.y, b.z, b.w};
        bf16x8 o;
#pragma unroll
        for (int j = 0; j < 8; ++j) o[j] = (bf16)f[j];
        *(bf16x8*)(dst + i) = o;
    }
}

// ---------------------------------------------------------------------------
// GEMM: C[M,N] = A[M,K] * B[N,K]^T + bias[N]. bf16 in, fp32 accum, OT out.
// Tile TM x 128, BK=64 as TWO stride-32 panels concatenated in LDS.
// MFMA operands SWAPPED (mfma(b,a)): D tile lands transposed -> each lane
// holds 4 CONSECUTIVE C columns (row=l15, col=l16*4+r) => bf16x4/float4
// C stores and a float4 bias load (4x fewer store instrs, same 32B segments).
// ---------------------------------------------------------------------------
template <int TM, typename OT>
__global__ __launch_bounds__(256) void gemm_bt(const bf16* __restrict__ A,
                                               const bf16* __restrict__ B,
                                               const float* __restrict__ bias,
                                               OT* __restrict__ C,
                                               int N, int K) {
    constexpr int MI = TM / 32;          // m-frags per wave
    constexpr int NCA = TM * 8;          // A 16B-chunks per K-tile
    __shared__ alignas(16) bf16 As[TM * 64];
    __shared__ alignas(16) bf16 Bs[128 * 64];
    const int tid = threadIdx.x;
    const int lane = tid & 63;
    const int wid = tid >> 6;
    const int wm = (wid >> 1) * (TM / 2), wn = (wid & 1) * 64;
    const int m0 = blockIdx.y * TM, n0 = blockIdx.x * 128;
    const int l15 = lane & 15, l16 = lane >> 4;

    f32x4 acc[MI][4] = {};

    const bf16* Abase = A + (size_t)m0 * K;
    const bf16* Bbase = B + (size_t)n0 * K;

    for (int k0 = 0; k0 < K; k0 += 64) {
#pragma unroll
        for (int c = tid; c < NCA; c += 256) {
            const int p = c / (TM * 4);
            const int r = (c % (TM * 4)) >> 2;
            const int ko = (c & 3) * 8 + p * 32;
            gl_lds16(Abase + (size_t)r * K + k0 + ko, &As[c * 8]);
        }
#pragma unroll
        for (int c = tid; c < 1024; c += 256) {
            const int p = c >> 9;
            const int r = (c & 511) >> 2;
            const int ko = (c & 3) * 8 + p * 32;
            gl_lds16(Bbase + (size_t)r * K + k0 + ko, &Bs[c * 8]);
        }
        __syncthreads();
#pragma unroll
        for (int h = 0; h < 2; ++h) {
            bf16x8 af[MI], bfr[4];
#pragma unroll
            for (int t = 0; t < MI; ++t)
                af[t] = *(const bf16x8*)&As[h * (TM * 32) + (wm + t * 16 + l15) * 32 + l16 * 8];
#pragma unroll
            for (int t = 0; t < 4; ++t)
                bfr[t] = *(const bf16x8*)&Bs[h * 4096 + (wn + t * 16 + l15) * 32 + l16 * 8];
#pragma unroll
            for (int i = 0; i < MI; ++i)
#pragma unroll
                for (int j = 0; j < 4; ++j)
                    acc[i][j] = MFMA_16x16x32(bfr[j], af[i], acc[i][j]);
        }
        __syncthreads();
    }

    // Swapped-D layout: lane holds C[m0+wm+i*16+l15][n0+wn+j*16+l16*4 + r]
#pragma unroll
    for (int j = 0; j < 4; ++j) {
        const int colb = n0 + wn + j * 16 + (l16 << 2);
        const float4 bv = *(const float4*)(bias + colb);
#pragma unroll
        for (int i = 0; i < MI; ++i) {
            const int row = m0 + wm + i * 16 + l15;
            if constexpr (sizeof(OT) == 2) {
                bf16x4 o;
                o[0] = (bf16)(acc[i][j][0] + bv.x);
                o[1] = (bf16)(acc[i][j][1] + bv.y);
                o[2] = (bf16)(acc[i][j][2] + bv.z);
                o[3] = (bf16)(acc[i][j][3] + bv.w);
                *(bf16x4*)&C[(size_t)row * N + colb] = o;
            } else {
                float4 o;
                o.x = acc[i][j][0] + bv.x;
                o.y = acc[i][j][1] + bv.y;
                o.z = acc[i][j][2] + bv.z;
                o.w = acc[i][j][3] + bv.w;
                *(float4*)&C[(size_t)row * N + colb] = o;
            }
        }
    }
}

// ---------------------------------------------------------------------------
// Banded causal attention, flash-style (same as round 3).
// ---------------------------------------------------------------------------
#define KS_STRIDE 72
#define PW_STRIDE 72
#define VT_ROWB 400

__global__ __launch_bounds__(256) void attn_kernel(const bf16* __restrict__ qkv,
                                                   bf16* __restrict__ ctx) {
    __shared__ alignas(16) bf16 Ks[192 * KS_STRIDE];
    __shared__ alignas(16) char Vt[64 * VT_ROWB];
    __shared__ alignas(16) bf16 Pbuf[4 * 16 * PW_STRIDE];

    const int tid = threadIdx.x;
    const int lane = tid & 63, wid = tid >> 6;
    const int l15 = lane & 15, l16 = lane >> 4;
    const int bid = blockIdx.y * 16 + blockIdx.x;
    const int swz = (bid & 7) * 128 + (bid >> 3);
    const int bh = swz >> 4, b = bh >> 3, h = bh & 7;
    const int q0 = (swz & 15) * 64;
    const int kv0 = (q0 > 128) ? (q0 - 128) : 0;
    const int nk = q0 + 64 - kv0;  // 64 / 128 / 192
    const size_t tokbase = (size_t)b * 1024;

    for (int c = tid; c < nk * 8; c += 256) {
        const int kk = c >> 3, dc = (c & 7) * 8;
        const bf16* src = qkv + (tokbase + kv0 + kk) * 1536 + h * 64 + dc + 512;
        *(uint4*)&Ks[kk * KS_STRIDE + dc] = *(const uint4*)src;
    }
    for (int c = tid; c < nk * 4; c += 256) {
        const int kp = c >> 3, dc = (c & 7) * 8;
        const bf16* s0 = qkv + (tokbase + kv0 + 2 * kp) * 1536 + h * 64 + dc + 1024;
        uint4 w0 = *(const uint4*)s0;
        uint4 w1 = *(const uint4*)(s0 + 1536);
        const unsigned short* a0 = (const unsigned short*)&w0;
        const unsigned short* a1 = (const unsigned short*)&w1;
        const int u = kp >> 2, wb = (kp & 3) * 4;
#pragma unroll
        for (int j = 0; j < 8; ++j) {
            const int d = dc + j;
            *(uint*)&Vt[d * VT_ROWB + ((u ^ (d & 7)) << 4) + wb] =
                (uint)a0[j] | ((uint)a1[j] << 16);
        }
    }

    const int qt0 = q0 + wid * 16;
    const bf16* qptr = qkv + (tokbase + qt0 + l15) * 1536 + h * 64;
    bf16x8 qa0 = *(const bf16x8*)(qptr + l16 * 8);
    bf16x8 qa1 = *(const bf16x8*)(qptr + 32 + l16 * 8);

    __syncthreads();

    bf16* Pw = &Pbuf[wid * 16 * PW_STRIDE];
    f32x4 of[4] = {};
    float mst[4], lst[4];
#pragma unroll
    for (int r = 0; r < 4; ++r) { mst[r] = -1e30f; lst[r] = 0.f; }

    const int ktstart = ((qt0 > 128) ? (qt0 - 128) : 0) & ~63;
    for (int kt = ktstart; kt <= qt0 + 15; kt += 64) {
        const int krel = kt - kv0;      // multiple of 64
        int kgn = ((qt0 + 15 - kt) >> 4) + 1;
        if (kgn > 4) kgn = 4;
        const int dlo = qt0 - 128 - kt;
        const int kglo = (dlo > 0) ? (dlo >> 4) : 0;

        f32x4 s[4] = {};
        __builtin_amdgcn_s_setprio(1);
#pragma unroll
        for (int kg = 0; kg < 4; ++kg) {
            if (kg >= kglo && kg < kgn) {   // wave-uniform
                const bf16* kb = &Ks[(krel + kg * 16 + l15) * KS_STRIDE + l16 * 8];
                s[kg] = MFMA_16x16x32(qa0, *(const bf16x8*)kb, s[kg]);
                s[kg] = MFMA_16x16x32(qa1, *(const bf16x8*)(kb + 32), s[kg]);
            }
        }
        __builtin_amdgcn_s_setprio(0);

#pragma unroll
        for (int r = 0; r < 4; ++r) {
            const int qa = qt0 + l16 * 4 + r;
            float v[4];
#pragma unroll
            for (int kg = 0; kg < 4; ++kg) {
                const int key = kt + kg * 16 + l15;
                const bool ok = (key <= qa) && (key >= qa - 128);
                v[kg] = ok ? s[kg][r] * 0.125f : -1e30f;
            }
            float mx = fmaxf(fmaxf(v[0], v[1]), fmaxf(v[2], v[3]));
#pragma unroll
            for (int off = 1; off < 16; off <<= 1)
                mx = fmaxf(mx, __shfl_xor(mx, off, 64));
            const float mnew = fmaxf(mst[r], mx);
            const float alpha = __expf(mst[r] - mnew);
            const float e0 = __expf(v[0] - mnew);
            const float e1 = __expf(v[1] - mnew);
            const float e2 = __expf(v[2] - mnew);
            const float e3 = __expf(v[3] - mnew);
            float rs = (e0 + e1) + (e2 + e3);
#pragma unroll
            for (int off = 1; off < 16; off <<= 1)
                rs += __shfl_xor(rs, off, 64);
            lst[r] = lst[r] * alpha + rs;
            mst[r] = mnew;
#pragma unroll
            for (int nt = 0; nt < 4; ++nt) of[nt][r] *= alpha;
            const int q = l16 * 4 + r;
            Pw[q * PW_STRIDE + l15] = (bf16)e0;
            Pw[q * PW_STRIDE + 16 + l15] = (bf16)e1;
            Pw[q * PW_STRIDE + 32 + l15] = (bf16)e2;
            Pw[q * PW_STRIDE + 48 + l15] = (bf16)e3;
        }
        __asm__ volatile("s_waitcnt lgkmcnt(0)" ::: "memory");

        const bool haveA = (kglo < 2);
        const bool haveB = (kgn > 2);
        const int ub = krel >> 3;
        __builtin_amdgcn_s_setprio(1);
        if (haveA) {
            bf16x8 pa = *(const bf16x8*)&Pw[l15 * PW_STRIDE + l16 * 8];
#pragma unroll
            for (int nt = 0; nt < 4; ++nt) {
                const int d = nt * 16 + l15;
                bf16x8 vb = *(const bf16x8*)&Vt[d * VT_ROWB + (((ub + l16) ^ (d & 7)) << 4)];
                of[nt] = MFMA_16x16x32(pa, vb, of[nt]);
            }
        }
        if (haveB) {
            bf16x8 pa = *(const bf16x8*)&Pw[l15 * PW_STRIDE + 32 + l16 * 8];
#pragma unroll
            for (int nt = 0; nt < 4; ++nt) {
                const int d = nt * 16 + l15;
                bf16x8 vb = *(const bf16x8*)&Vt[d * VT_ROWB + (((ub + 4 + l16) ^ (d & 7)) << 4)];
                of[nt] = MFMA_16x16x32(pa, vb, of[nt]);
            }
        }
        __builtin_amdgcn_s_setprio(0);
    }

    float linv[4];
#pragma unroll
    for (int r = 0; r < 4; ++r) linv[r] = 1.0f / lst[r];
    bf16* cbase = ctx + (tokbase + qt0) * 512 + h * 64;
#pragma unroll
    for (int nt = 0; nt < 4; ++nt)
#pragma unroll
        for (int r = 0; r < 4; ++r) {
            const int q = l16 * 4 + r;
            cbase[(size_t)q * 512 + nt * 16 + l15] = (bf16)(of[nt][r] * linv[r]);
        }
}

// ---------------------------------------------------------------------------
// MEASUREMENT ROUND (retry): each kernel launched 3x (idempotent re-writes;
// ordering respects the ctx==xn alias: all QKV-GEMM passes read xn before
// attn clobbers it). dur_us = dur1 + 2*(sum of kernel times) + ~8 gaps.
// ---------------------------------------------------------------------------
extern "C" void kernel_launch(void* const* d_in, const int* in_sizes, int n_in,
                              void* d_out, int out_size, void* d_ws, size_t ws_size,
                              hipStream_t stream) {
    const float* x     = (const float*)d_in[0];
    // d_in[1] = x_lengths (unused by reference)
    const float* gamma = (const float*)d_in[2];
    const float* beta  = (const float*)d_in[3];
    const float* w_in  = (const float*)d_in[4];
    const float* b_in  = (const float*)d_in[5];
    const float* w_out = (const float*)d_in[6];
    const float* b_out = (const float*)d_in[7];
    float* out = (float*)d_out;

    char* ws = (char*)d_ws;
    bf16* cw_in  = (bf16*)ws;                   // 786432 elems (1.5 MB)
    bf16* cw_out = cw_in + 786432;              // 262144 (0.5 MB)
    bf16* xn     = (bf16*)(ws + (4u << 20));    // 8 MB
    bf16* qkv    = (bf16*)(ws + (12u << 20));   // 24 MB
    bf16* ctx    = xn;                          // xn dead after QKV GEMM

    for (int rep = 0; rep < 3; ++rep)
        prep_kernel<<<2560, 256, 0, stream>>>(x, gamma, beta, w_in, w_out, xn, cw_in, cw_out);
    for (int rep = 0; rep < 3; ++rep)
        gemm_bt<128, bf16><<<dim3(12, 64), 256, 0, stream>>>(xn, cw_in, b_in, qkv, 1536, 512);
    for (int rep = 0; rep < 3; ++rep)
        attn_kernel<<<dim3(16, 64), 256, 0, stream>>>(qkv, ctx);
    for (int rep = 0; rep < 3; ++rep)
        gemm_bt<64, float><<<dim3(4, 128), 256, 0, stream>>>(ctx, cw_out, b_out, out, 512, 512);
}

// Round 6
// 145.912 us; speedup vs baseline: 1.8312x; 1.8312x over previous
//
#include <hip/hip_runtime.h>
#include <stdint.h>

typedef __bf16 bf16;
typedef __bf16 bf16x4 __attribute__((ext_vector_type(4)));
typedef __bf16 bf16x8 __attribute__((ext_vector_type(8)));
typedef float f32x4 __attribute__((ext_vector_type(4)));

#define MFMA_16x16x32(a, b, c) __builtin_amdgcn_mfma_f32_16x16x32_bf16((a), (b), (c), 0, 0, 0)

// async global->LDS, 16B per lane. LDS dest must be wave-uniform base + lane*16.
__device__ __forceinline__ void gl_lds16(const bf16* g, bf16* l) {
    __builtin_amdgcn_global_load_lds(
        (const __attribute__((address_space(1))) void*)g,
        (__attribute__((address_space(3))) void*)l, 16, 0, 0);
}

// ---------------------------------------------------------------------------
// prep: blocks [0,2048) = LayerNorm (4 rows each, f32 in, bf16 out, f32 g/b);
//       blocks [2048,2432) = w_in f32->bf16; [2432,2560) = w_out f32->bf16.
// ---------------------------------------------------------------------------
__global__ __launch_bounds__(256) void prep_kernel(const float* __restrict__ x,
                                                   const float* __restrict__ gamma,
                                                   const float* __restrict__ beta,
                                                   const float* __restrict__ w_in,
                                                   const float* __restrict__ w_out,
                                                   bf16* __restrict__ xn,
                                                   bf16* __restrict__ cw_in,
                                                   bf16* __restrict__ cw_out) {
    const int bid = blockIdx.x;
    if (bid < 2048) {
        const int lane = threadIdx.x & 63;
        const int row = (bid << 2) + (threadIdx.x >> 6);
        const size_t base = (size_t)row * 512 + lane * 8;
        const float* xf = x + base;
        float4 a = *(const float4*)xf;
        float4 b = *(const float4*)(xf + 4);
        float f[8] = {a.x, a.y, a.z, a.w, b.x, b.y, b.z, b.w};
        float s = 0.f;
#pragma unroll
        for (int j = 0; j < 8; ++j) s += f[j];
#pragma unroll
        for (int off = 32; off >= 1; off >>= 1) s += __shfl_xor(s, off, 64);
        const float mu = s * (1.0f / 512.0f);
        float vs = 0.f;
#pragma unroll
        for (int j = 0; j < 8; ++j) { float d = f[j] - mu; vs += d * d; }
#pragma unroll
        for (int off = 32; off >= 1; off >>= 1) vs += __shfl_xor(vs, off, 64);
        const float rstd = rsqrtf(vs * (1.0f / 512.0f) + 1e-5f);
        float4 g0 = *(const float4*)(gamma + lane * 8);
        float4 g1 = *(const float4*)(gamma + lane * 8 + 4);
        float4 b0 = *(const float4*)(beta + lane * 8);
        float4 b1 = *(const float4*)(beta + lane * 8 + 4);
        float gg[8] = {g0.x, g0.y, g0.z, g0.w, g1.x, g1.y, g1.z, g1.w};
        float bb[8] = {b0.x, b0.y, b0.z, b0.w, b1.x, b1.y, b1.z, b1.w};
        bf16x8 o;
#pragma unroll
        for (int j = 0; j < 8; ++j)
            o[j] = (bf16)((f[j] - mu) * rstd * gg[j] + bb[j]);
        *(bf16x8*)(xn + base) = o;
    } else {
        const float* src;
        bf16* dst;
        int base;
        if (bid < 2432) { src = w_in;  dst = cw_in;  base = (bid - 2048) * 2048; }
        else            { src = w_out; dst = cw_out; base = (bid - 2432) * 2048; }
        const int i = base + threadIdx.x * 8;
        float4 a = *(const float4*)(src + i);
        float4 b = *(const float4*)(src + i + 4);
        float f[8] = {a.x, a.y, a.z, a.w, b.x, b.y, b.z, b.w};
        bf16x8 o;
#pragma unroll
        for (int j = 0; j < 8; ++j) o[j] = (bf16)f[j];
        *(bf16x8*)(dst + i) = o;
    }
}

// ---------------------------------------------------------------------------
// GEMM: C[M,N] = A[M,K] * B[N,K]^T + bias[N]. bf16 in, fp32 accum, OT out.
// Tile TM x 128, BK=64 as TWO stride-32 panels concatenated in LDS.
// K is a compile-time constant (KK): the k0 loop fully unrolls, all staging
// address chains become loop-invariant bases + immediate offsets (k0*2B fits
// the 13-bit global / 16-bit DS offset immediates) -> staging VALU shrinks.
// MFMA operands SWAPPED (mfma(b,a)): D tile transposed -> lane holds 4
// consecutive C columns => bf16x4/float4 stores + float4 bias load.
// ---------------------------------------------------------------------------
template <int TM, int KK, typename OT>
__global__ __launch_bounds__(256) void gemm_bt(const bf16* __restrict__ A,
                                               const bf16* __restrict__ B,
                                               const float* __restrict__ bias,
                                               OT* __restrict__ C,
                                               int N) {
    constexpr int MI = TM / 32;          // m-frags per wave
    constexpr int NCA = TM * 8;          // A 16B-chunks per K-tile
    __shared__ alignas(16) bf16 As[TM * 64];
    __shared__ alignas(16) bf16 Bs[128 * 64];
    const int tid = threadIdx.x;
    const int lane = tid & 63;
    const int wid = tid >> 6;
    const int wm = (wid >> 1) * (TM / 2), wn = (wid & 1) * 64;
    const int m0 = blockIdx.y * TM, n0 = blockIdx.x * 128;
    const int l15 = lane & 15, l16 = lane >> 4;

    f32x4 acc[MI][4] = {};

    const bf16* Abase = A + (size_t)m0 * KK;
    const bf16* Bbase = B + (size_t)n0 * KK;

#pragma unroll
    for (int k0 = 0; k0 < KK; k0 += 64) {
#pragma unroll
        for (int c = tid; c < NCA; c += 256) {
            const int p = c / (TM * 4);
            const int r = (c % (TM * 4)) >> 2;
            const int ko = (c & 3) * 8 + p * 32;
            gl_lds16(Abase + (size_t)r * KK + k0 + ko, &As[c * 8]);
        }
#pragma unroll
        for (int c = tid; c < 1024; c += 256) {
            const int p = c >> 9;
            const int r = (c & 511) >> 2;
            const int ko = (c & 3) * 8 + p * 32;
            gl_lds16(Bbase + (size_t)r * KK + k0 + ko, &Bs[c * 8]);
        }
        __syncthreads();
#pragma unroll
        for (int h = 0; h < 2; ++h) {
            bf16x8 af[MI], bfr[4];
#pragma unroll
            for (int t = 0; t < MI; ++t)
                af[t] = *(const bf16x8*)&As[h * (TM * 32) + (wm + t * 16 + l15) * 32 + l16 * 8];
#pragma unroll
            for (int t = 0; t < 4; ++t)
                bfr[t] = *(const bf16x8*)&Bs[h * 4096 + (wn + t * 16 + l15) * 32 + l16 * 8];
#pragma unroll
            for (int i = 0; i < MI; ++i)
#pragma unroll
                for (int j = 0; j < 4; ++j)
                    acc[i][j] = MFMA_16x16x32(bfr[j], af[i], acc[i][j]);
        }
        __syncthreads();
    }

    // Swapped-D layout: lane holds C[m0+wm+i*16+l15][n0+wn+j*16+l16*4 + r]
#pragma unroll
    for (int j = 0; j < 4; ++j) {
        const int colb = n0 + wn + j * 16 + (l16 << 2);
        const float4 bv = *(const float4*)(bias + colb);
#pragma unroll
        for (int i = 0; i < MI; ++i) {
            const int row = m0 + wm + i * 16 + l15;
            if constexpr (sizeof(OT) == 2) {
                bf16x4 o;
                o[0] = (bf16)(acc[i][j][0] + bv.x);
                o[1] = (bf16)(acc[i][j][1] + bv.y);
                o[2] = (bf16)(acc[i][j][2] + bv.z);
                o[3] = (bf16)(acc[i][j][3] + bv.w);
                *(bf16x4*)&C[(size_t)row * N + colb] = o;
            } else {
                float4 o;
                o.x = acc[i][j][0] + bv.x;
                o.y = acc[i][j][1] + bv.y;
                o.z = acc[i][j][2] + bv.z;
                o.w = acc[i][j][3] + bv.w;
                *(float4*)&C[(size_t)row * N + colb] = o;
            }
        }
    }
}

// ---------------------------------------------------------------------------
// Banded causal attention, flash-style. Block = 64 queries of one (b,h);
// 4 waves, each a 16-query tile with online softmax, kt-step 64 with
// wave-uniform 16-key-group edge skip.
// LDS cut to 54,272 B -> 3 blocks/CU (was 62.5 KB -> 2): +50% waves/SIMD.
//  - Ks dense [192][64] bf16, 16B-chunk XOR swizzle (chunk ^= row&7):
//    reads keep all 32 banks busy (2 lanes per 4-bank group), 3 KB smaller.
//  - Vt [64][384 B]: swizzled unit index stays < 24, pad removed.
//  - Pbuf per-wave 16x40 bf16, TIME-SHARED between the two 32-key granules
//    (write A -> lgkm -> PV-A -> write B -> lgkm -> PV-B); per-wave private,
//    in-order DS ops make the reuse safe. 9.2 KB -> 5 KB.
// T13 defer-max: skip rescale unless __any(mx > m+8); P bounded by e^8.
// ---------------------------------------------------------------------------
__global__ __launch_bounds__(256, 3) void attn_kernel(const bf16* __restrict__ qkv,
                                                      bf16* __restrict__ ctx) {
    __shared__ alignas(16) bf16 Ks[192 * 64];
    __shared__ alignas(16) char Vt[64 * 384];
    __shared__ alignas(16) bf16 Pbuf[4 * 16 * 40];

    const int tid = threadIdx.x;
    const int lane = tid & 63, wid = tid >> 6;
    const int l15 = lane & 15, l16 = lane >> 4;
    // XCD-aware bijective swizzle (1024 % 8 == 0)
    const int bid = blockIdx.y * 16 + blockIdx.x;
    const int swz = (bid & 7) * 128 + (bid >> 3);
    const int bh = swz >> 4, b = bh >> 3, h = bh & 7;
    const int q0 = (swz & 15) * 64;
    const int kv0 = (q0 > 128) ? (q0 - 128) : 0;
    const int nk = q0 + 64 - kv0;  // 64 / 128 / 192
    const size_t tokbase = (size_t)b * 1024;

    // K: dense rows, 16B chunk j stored at (j ^ (row&7))
    for (int c = tid; c < nk * 8; c += 256) {
        const int kk = c >> 3, j = c & 7;
        const bf16* src = qkv + (tokbase + kv0 + kk) * 1536 + h * 64 + j * 8 + 512;
        *(uint4*)&Ks[kk * 64 + ((j ^ (kk & 7)) << 3)] = *(const uint4*)src;
    }
    // V: transposed [d][key], paired keys per dword, XOR-swizzled 16B units
    for (int c = tid; c < nk * 4; c += 256) {
        const int kp = c >> 3, dc = (c & 7) * 8;
        const bf16* s0 = qkv + (tokbase + kv0 + 2 * kp) * 1536 + h * 64 + dc + 1024;
        uint4 w0 = *(const uint4*)s0;
        uint4 w1 = *(const uint4*)(s0 + 1536);
        const unsigned short* a0 = (const unsigned short*)&w0;
        const unsigned short* a1 = (const unsigned short*)&w1;
        const int u = kp >> 2, wb = (kp & 3) * 4;
#pragma unroll
        for (int j = 0; j < 8; ++j) {
            const int d = dc + j;
            *(uint*)&Vt[d * 384 + ((u ^ (d & 7)) << 4) + wb] =
                (uint)a0[j] | ((uint)a1[j] << 16);
        }
    }

    const int qt0 = q0 + wid * 16;
    const bf16* qptr = qkv + (tokbase + qt0 + l15) * 1536 + h * 64;
    bf16x8 qa0 = *(const bf16x8*)(qptr + l16 * 8);
    bf16x8 qa1 = *(const bf16x8*)(qptr + 32 + l16 * 8);

    __syncthreads();

    bf16* Pw = &Pbuf[wid * 16 * 40];
    f32x4 of[4] = {};
    float mst[4], lst[4];
#pragma unroll
    for (int r = 0; r < 4; ++r) { mst[r] = -1e30f; lst[r] = 0.f; }

    const int ktstart = ((qt0 > 128) ? (qt0 - 128) : 0) & ~63;
    for (int kt = ktstart; kt <= qt0 + 15; kt += 64) {
        const int krel = kt - kv0;      // multiple of 64
        int kgn = ((qt0 + 15 - kt) >> 4) + 1;
        if (kgn > 4) kgn = 4;
        const int dlo = qt0 - 128 - kt;
        const int kglo = (dlo > 0) ? (dlo >> 4) : 0;

        f32x4 s[4] = {};
        __builtin_amdgcn_s_setprio(1);
#pragma unroll
        for (int kg = 0; kg < 4; ++kg) {
            if (kg >= kglo && kg < kgn) {   // wave-uniform
                const int row = krel + kg * 16 + l15;
                const bf16* kb0 = &Ks[row * 64 + ((l16 ^ (row & 7)) << 3)];
                const bf16* kb1 = &Ks[row * 64 + (((4 + l16) ^ (row & 7)) << 3)];
                s[kg] = MFMA_16x16x32(qa0, *(const bf16x8*)kb0, s[kg]);
                s[kg] = MFMA_16x16x32(qa1, *(const bf16x8*)kb1, s[kg]);
            }
        }
        __builtin_amdgcn_s_setprio(0);

        const bool haveA = (kglo < 2);
        const bool haveB = (kgn > 2);
        float e2s[4], e3s[4];
#pragma unroll
        for (int r = 0; r < 4; ++r) {
            const int qa = qt0 + l16 * 4 + r;
            float v[4];
#pragma unroll
            for (int kg = 0; kg < 4; ++kg) {
                const int key = kt + kg * 16 + l15;
                v[kg] = ((unsigned)(qa - key) <= 128u) ? s[kg][r] * 0.125f : -1e30f;
            }
            float mx = fmaxf(fmaxf(v[0], v[1]), fmaxf(v[2], v[3]));
#pragma unroll
            for (int off = 1; off < 16; off <<= 1)
                mx = fmaxf(mx, __shfl_xor(mx, off, 64));
            if (__any(mx > mst[r] + 8.0f)) {   // T13: rescale only when needed
                const float mnew = fmaxf(mst[r], mx);
                const float alpha = __expf(mst[r] - mnew);
                lst[r] *= alpha;
#pragma unroll
                for (int nt = 0; nt < 4; ++nt) of[nt][r] *= alpha;
                mst[r] = mnew;
            }
            const float e0 = __expf(v[0] - mst[r]);  // masked -> 0; bounded by e^8
            const float e1 = __expf(v[1] - mst[r]);
            const float e2 = __expf(v[2] - mst[r]);
            const float e3 = __expf(v[3] - mst[r]);
            float rs = (e0 + e1) + (e2 + e3);
#pragma unroll
            for (int off = 1; off < 16; off <<= 1)
                rs += __shfl_xor(rs, off, 64);
            lst[r] += rs;
            e2s[r] = e2; e3s[r] = e3;
            if (haveA) {
                const int q = l16 * 4 + r;
                Pw[q * 40 + l15] = (bf16)e0;
                Pw[q * 40 + 16 + l15] = (bf16)e1;
            }
        }

        const int ub = krel >> 3;
        __builtin_amdgcn_s_setprio(1);
        if (haveA) {
            __asm__ volatile("s_waitcnt lgkmcnt(0)" ::: "memory");
            bf16x8 pa = *(const bf16x8*)&Pw[l15 * 40 + l16 * 8];
#pragma unroll
            for (int nt = 0; nt < 4; ++nt) {
                const int d = nt * 16 + l15;
                bf16x8 vb = *(const bf16x8*)&Vt[d * 384 + (((ub + l16) ^ (d & 7)) << 4)];
                of[nt] = MFMA_16x16x32(pa, vb, of[nt]);
            }
        }
        if (haveB) {
#pragma unroll
            for (int r = 0; r < 4; ++r) {
                const int q = l16 * 4 + r;
                Pw[q * 40 + l15] = (bf16)e2s[r];
                Pw[q * 40 + 16 + l15] = (bf16)e3s[r];
            }
            __asm__ volatile("s_waitcnt lgkmcnt(0)" ::: "memory");
            bf16x8 pa = *(const bf16x8*)&Pw[l15 * 40 + l16 * 8];
#pragma unroll
            for (int nt = 0; nt < 4; ++nt) {
                const int d = nt * 16 + l15;
                bf16x8 vb = *(const bf16x8*)&Vt[d * 384 + (((ub + 4 + l16) ^ (d & 7)) << 4)];
                of[nt] = MFMA_16x16x32(pa, vb, of[nt]);
            }
        }
        __builtin_amdgcn_s_setprio(0);
    }

    float linv[4];
#pragma unroll
    for (int r = 0; r < 4; ++r) linv[r] = 1.0f / lst[r];
    bf16* cbase = ctx + (tokbase + qt0) * 512 + h * 64;
#pragma unroll
    for (int nt = 0; nt < 4; ++nt)
#pragma unroll
        for (int r = 0; r < 4; ++r) {
            const int q = l16 * 4 + r;
            cbase[(size_t)q * 512 + nt * 16 + l15] = (bf16)(of[nt][r] * linv[r]);
        }
}

// ---------------------------------------------------------------------------
extern "C" void kernel_launch(void* const* d_in, const int* in_sizes, int n_in,
                              void* d_out, int out_size, void* d_ws, size_t ws_size,
                              hipStream_t stream) {
    const float* x     = (const float*)d_in[0];
    // d_in[1] = x_lengths (unused by reference)
    const float* gamma = (const float*)d_in[2];
    const float* beta  = (const float*)d_in[3];
    const float* w_in  = (const float*)d_in[4];
    const float* b_in  = (const float*)d_in[5];
    const float* w_out = (const float*)d_in[6];
    const float* b_out = (const float*)d_in[7];
    float* out = (float*)d_out;

    char* ws = (char*)d_ws;
    bf16* cw_in  = (bf16*)ws;                   // 786432 elems (1.5 MB)
    bf16* cw_out = cw_in + 786432;              // 262144 (0.5 MB)
    bf16* xn     = (bf16*)(ws + (4u << 20));    // 8 MB
    bf16* qkv    = (bf16*)(ws + (12u << 20));   // 24 MB
    bf16* ctx    = xn;                          // xn dead after QKV GEMM

    prep_kernel<<<2560, 256, 0, stream>>>(x, gamma, beta, w_in, w_out, xn, cw_in, cw_out);
    gemm_bt<128, 512, bf16><<<dim3(12, 64), 256, 0, stream>>>(xn, cw_in, b_in, qkv, 1536);
    attn_kernel<<<dim3(16, 64), 256, 0, stream>>>(qkv, ctx);
    gemm_bt<64, 512, float><<<dim3(4, 128), 256, 0, stream>>>(ctx, cw_out, b_out, out, 512);
}

// Round 7
// 138.553 us; speedup vs baseline: 1.9284x; 1.0531x over previous
//
#include <hip/hip_runtime.h>
#include <stdint.h>

typedef __bf16 bf16;
typedef __bf16 bf16x8 __attribute__((ext_vector_type(8)));
typedef float f32x4 __attribute__((ext_vector_type(4)));

#define MFMA_16x16x32(a, b, c) __builtin_amdgcn_mfma_f32_16x16x32_bf16((a), (b), (c), 0, 0, 0)

// async global->LDS, 16B per lane. LDS dest must be wave-uniform base + lane*16.
__device__ __forceinline__ void gl_lds16(const bf16* g, bf16* l) {
    __builtin_amdgcn_global_load_lds(
        (const __attribute__((address_space(1))) void*)g,
        (__attribute__((address_space(3))) void*)l, 16, 0, 0);
}

// ---------------------------------------------------------------------------
// prep: blocks [0,2048) = LayerNorm (4 rows each, f32 in, bf16 out, f32 g/b);
//       blocks [2048,2432) = w_in f32->bf16; [2432,2560) = w_out f32->bf16.
// ---------------------------------------------------------------------------
__global__ __launch_bounds__(256) void prep_kernel(const float* __restrict__ x,
                                                   const float* __restrict__ gamma,
                                                   const float* __restrict__ beta,
                                                   const float* __restrict__ w_in,
                                                   const float* __restrict__ w_out,
                                                   bf16* __restrict__ xn,
                                                   bf16* __restrict__ cw_in,
                                                   bf16* __restrict__ cw_out) {
    const int bid = blockIdx.x;
    if (bid < 2048) {
        const int lane = threadIdx.x & 63;
        const int row = (bid << 2) + (threadIdx.x >> 6);
        const size_t base = (size_t)row * 512 + lane * 8;
        const float* xf = x + base;
        float4 a = *(const float4*)xf;
        float4 b = *(const float4*)(xf + 4);
        float f[8] = {a.x, a.y, a.z, a.w, b.x, b.y, b.z, b.w};
        float s = 0.f;
#pragma unroll
        for (int j = 0; j < 8; ++j) s += f[j];
#pragma unroll
        for (int off = 32; off >= 1; off >>= 1) s += __shfl_xor(s, off, 64);
        const float mu = s * (1.0f / 512.0f);
        float vs = 0.f;
#pragma unroll
        for (int j = 0; j < 8; ++j) { float d = f[j] - mu; vs += d * d; }
#pragma unroll
        for (int off = 32; off >= 1; off >>= 1) vs += __shfl_xor(vs, off, 64);
        const float rstd = rsqrtf(vs * (1.0f / 512.0f) + 1e-5f);
        float4 g0 = *(const float4*)(gamma + lane * 8);
        float4 g1 = *(const float4*)(gamma + lane * 8 + 4);
        float4 b0 = *(const float4*)(beta + lane * 8);
        float4 b1 = *(const float4*)(beta + lane * 8 + 4);
        float gg[8] = {g0.x, g0.y, g0.z, g0.w, g1.x, g1.y, g1.z, g1.w};
        float bb[8] = {b0.x, b0.y, b0.z, b0.w, b1.x, b1.y, b1.z, b1.w};
        bf16x8 o;
#pragma unroll
        for (int j = 0; j < 8; ++j)
            o[j] = (bf16)((f[j] - mu) * rstd * gg[j] + bb[j]);
        *(bf16x8*)(xn + base) = o;
    } else {
        const float* src;
        bf16* dst;
        int base;
        if (bid < 2432) { src = w_in;  dst = cw_in;  base = (bid - 2048) * 2048; }
        else            { src = w_out; dst = cw_out; base = (bid - 2432) * 2048; }
        const int i = base + threadIdx.x * 8;
        float4 a = *(const float4*)(src + i);
        float4 b = *(const float4*)(src + i + 4);
        float f[8] = {a.x, a.y, a.z, a.w, b.x, b.y, b.z, b.w};
        bf16x8 o;
#pragma unroll
        for (int j = 0; j < 8; ++j) o[j] = (bf16)f[j];
        *(bf16x8*)(dst + i) = o;
    }
}

// ---------------------------------------------------------------------------
// GEMM: C[M,N] = A[M,K] * B[N,K]^T + bias[N]. bf16 in, fp32 accum, OT out.
// Tile TM x 128, BK=64 as TWO stride-32 panels concatenated in LDS:
// chunk c -> panel p=c/(TM*4), row r=(c%(TM*4))>>2, koff (c&3)*8+p*32,
// LDS addr = c*8 (contiguous lane order, valid for global_load_lds), and
// frag reads keep the phase-optimal 16-dword row stride. 8 K-iters (vs 16)
// -> half the barrier/vmcnt(0) drains of the BK=32 m97 structure.
// ---------------------------------------------------------------------------
template <int TM, typename OT>
__global__ __launch_bounds__(256) void gemm_bt(const bf16* __restrict__ A,
                                               const bf16* __restrict__ B,
                                               const float* __restrict__ bias,
                                               OT* __restrict__ C,
                                               int N, int K) {
    constexpr int MI = TM / 32;          // m-frags per wave
    constexpr int NCA = TM * 8;          // A 16B-chunks per K-tile
    __shared__ alignas(16) bf16 As[TM * 64];
    __shared__ alignas(16) bf16 Bs[128 * 64];
    const int tid = threadIdx.x;
    const int lane = tid & 63;
    const int wid = tid >> 6;
    const int wm = (wid >> 1) * (TM / 2), wn = (wid & 1) * 64;
    const int m0 = blockIdx.y * TM, n0 = blockIdx.x * 128;
    const int l15 = lane & 15, l16 = lane >> 4;

    f32x4 acc[MI][4] = {};

    const bf16* Abase = A + (size_t)m0 * K;
    const bf16* Bbase = B + (size_t)n0 * K;

    for (int k0 = 0; k0 < K; k0 += 64) {
#pragma unroll
        for (int c = tid; c < NCA; c += 256) {
            const int p = c / (TM * 4);
            const int r = (c % (TM * 4)) >> 2;
            const int ko = (c & 3) * 8 + p * 32;
            gl_lds16(Abase + (size_t)r * K + k0 + ko, &As[c * 8]);
        }
#pragma unroll
        for (int c = tid; c < 1024; c += 256) {
            const int p = c >> 9;
            const int r = (c & 511) >> 2;
            const int ko = (c & 3) * 8 + p * 32;
            gl_lds16(Bbase + (size_t)r * K + k0 + ko, &Bs[c * 8]);
        }
        __syncthreads();
#pragma unroll
        for (int h = 0; h < 2; ++h) {
            bf16x8 af[MI], bfr[4];
#pragma unroll
            for (int t = 0; t < MI; ++t)
                af[t] = *(const bf16x8*)&As[h * (TM * 32) + (wm + t * 16 + l15) * 32 + l16 * 8];
#pragma unroll
            for (int t = 0; t < 4; ++t)
                bfr[t] = *(const bf16x8*)&Bs[h * 4096 + (wn + t * 16 + l15) * 32 + l16 * 8];
#pragma unroll
            for (int i = 0; i < MI; ++i)
#pragma unroll
                for (int j = 0; j < 4; ++j)
                    acc[i][j] = MFMA_16x16x32(af[i], bfr[j], acc[i][j]);
        }
        __syncthreads();
    }

    // C/D layout: col = lane&15, row = (lane>>4)*4 + reg
#pragma unroll
    for (int j = 0; j < 4; ++j) {
        const int col = n0 + wn + j * 16 + l15;
        const float bv = bias[col];
#pragma unroll
        for (int i = 0; i < MI; ++i) {
            const int rbase = m0 + wm + i * 16 + l16 * 4;
#pragma unroll
            for (int r = 0; r < 4; ++r)
                C[(size_t)(rbase + r) * N + col] = (OT)(acc[i][j][r] + bv);
        }
    }
}

// ---------------------------------------------------------------------------
// Banded causal attention, flash-style. Block = 64 queries of one (b,h);
// 4 waves, each a 16-query tile with online softmax.
// Ks[key][d] stride 72 (b128-friendly). V stored NATURAL Vn[key][d] stride 74:
// staging via 4x b32 writes (conflict-free); PV B-frags read scalar
// (l16-groups at +8 banks, l15 pairs same-dword broadcast -> conflict-free).
// Row clamp kills OOB-garbage x0 NaN hazard.
// ---------------------------------------------------------------------------
#define KS_STRIDE 72
#define VN_STRIDE 74
#define PW_STRIDE 40

__global__ __launch_bounds__(256) void attn_kernel(const bf16* __restrict__ qkv,
                                                   bf16* __restrict__ ctx) {
    __shared__ alignas(16) bf16 Ks[192 * KS_STRIDE];
    __shared__ alignas(16) bf16 Vn[192 * VN_STRIDE];
    __shared__ alignas(16) bf16 Pbuf[4 * 16 * PW_STRIDE];

    const int tid = threadIdx.x;
    const int lane = tid & 63, wid = tid >> 6;
    const int l15 = lane & 15, l16 = lane >> 4;
    const int bh = blockIdx.y, b = bh >> 3, h = bh & 7;
    const int q0 = blockIdx.x * 64;
    const int kv0 = (q0 > 128) ? (q0 - 128) : 0;
    const int nk = q0 + 64 - kv0;  // 64 / 128 / 192
    const size_t tokbase = (size_t)b * 1024;

    for (int c = tid; c < nk * 8; c += 256) {
        const int kk = c >> 3, dc = (c & 7) * 8;
        const bf16* src = qkv + (tokbase + kv0 + kk) * 1536 + h * 64 + dc;
        uint4 kw = *(const uint4*)(src + 512);
        *(uint4*)&Ks[kk * KS_STRIDE + dc] = kw;
        uint4 vw = *(const uint4*)(src + 1024);
        uint* vdst = (uint*)&Vn[kk * VN_STRIDE + dc];
        vdst[0] = vw.x; vdst[1] = vw.y; vdst[2] = vw.z; vdst[3] = vw.w;
    }

    const int qt0 = q0 + wid * 16;
    const bf16* qptr = qkv + (tokbase + qt0 + l15) * 1536 + h * 64;
    bf16x8 qa0 = *(const bf16x8*)(qptr + l16 * 8);
    bf16x8 qa1 = *(const bf16x8*)(qptr + 32 + l16 * 8);

    __syncthreads();

    bf16* Pw = &Pbuf[wid * 16 * PW_STRIDE];
    f32x4 of[4] = {};
    float mst[4], lst[4];
#pragma unroll
    for (int r = 0; r < 4; ++r) { mst[r] = -1e30f; lst[r] = 0.f; }

    const int ktstart = ((qt0 > 128) ? (qt0 - 128) : 0) & ~31;
    for (int kt = ktstart; kt <= qt0 + 15; kt += 32) {
        const int krel = kt - kv0;
        f32x4 s0 = {}, s1 = {};
        {
            const bf16* kb0 = &Ks[(krel + l15) * KS_STRIDE + l16 * 8];
            const bf16* kb1 = kb0 + 16 * KS_STRIDE;
            s0 = MFMA_16x16x32(qa0, *(const bf16x8*)kb0, s0);
            s0 = MFMA_16x16x32(qa1, *(const bf16x8*)(kb0 + 32), s0);
            s1 = MFMA_16x16x32(qa0, *(const bf16x8*)kb1, s1);
            s1 = MFMA_16x16x32(qa1, *(const bf16x8*)(kb1 + 32), s1);
        }
        float e0[4], e1[4];
#pragma unroll
        for (int r = 0; r < 4; ++r) {
            const int qa = qt0 + l16 * 4 + r;
            const int kg0 = kt + l15;
            const int kg1 = kg0 + 16;
            const bool ok0 = (kg0 <= qa) && (kg0 >= qa - 128);
            const bool ok1 = (kg1 <= qa) && (kg1 >= qa - 128);
            float v0 = ok0 ? s0[r] * 0.125f : -1e30f;
            float v1 = ok1 ? s1[r] * 0.125f : -1e30f;
            float mx = fmaxf(v0, v1);
#pragma unroll
            for (int off = 1; off < 16; off <<= 1)
                mx = fmaxf(mx, __shfl_xor(mx, off, 64));
            const float mnew = fmaxf(mst[r], mx);
            const float alpha = __expf(mst[r] - mnew);
            e0[r] = ok0 ? __expf(v0 - mnew) : 0.f;
            e1[r] = ok1 ? __expf(v1 - mnew) : 0.f;
            float rs = e0[r] + e1[r];
#pragma unroll
            for (int off = 1; off < 16; off <<= 1)
                rs += __shfl_xor(rs, off, 64);
            lst[r] = lst[r] * alpha + rs;
            mst[r] = mnew;
#pragma unroll
            for (int nt = 0; nt < 4; ++nt) of[nt][r] *= alpha;
        }
        // P: D-layout -> LDS -> A-operand layout
#pragma unroll
        for (int r = 0; r < 4; ++r) {
            const int q = l16 * 4 + r;
            Pw[q * PW_STRIDE + l15] = (bf16)e0[r];
            Pw[q * PW_STRIDE + 16 + l15] = (bf16)e1[r];
        }
        __asm__ volatile("s_waitcnt lgkmcnt(0)" ::: "memory");
        bf16x8 pa = *(const bf16x8*)&Pw[l15 * PW_STRIDE + l16 * 8];
        // O += P V : B-frag scalar from natural Vn, rows clamped to staged range
        int row[8];
#pragma unroll
        for (int j = 0; j < 8; ++j) {
            int rr = krel + l16 * 8 + j;
            row[j] = (rr < nk) ? rr : (nk - 1);
        }
#pragma unroll
        for (int nt = 0; nt < 4; ++nt) {
            bf16x8 vb;
#pragma unroll
            for (int j = 0; j < 8; ++j)
                vb[j] = Vn[row[j] * VN_STRIDE + nt * 16 + l15];
            of[nt] = MFMA_16x16x32(pa, vb, of[nt]);
        }
        __asm__ volatile("s_waitcnt lgkmcnt(0)" ::: "memory");
    }

    float linv[4];
#pragma unroll
    for (int r = 0; r < 4; ++r) linv[r] = 1.0f / lst[r];
    bf16* cbase = ctx + (tokbase + qt0) * 512 + h * 64;
#pragma unroll
    for (int nt = 0; nt < 4; ++nt)
#pragma unroll
        for (int r = 0; r < 4; ++r) {
            const int q = l16 * 4 + r;
            cbase[(size_t)q * 512 + nt * 16 + l15] = (bf16)(of[nt][r] * linv[r]);
        }
}

// ---------------------------------------------------------------------------
extern "C" void kernel_launch(void* const* d_in, const int* in_sizes, int n_in,
                              void* d_out, int out_size, void* d_ws, size_t ws_size,
                              hipStream_t stream) {
    const float* x     = (const float*)d_in[0];
    // d_in[1] = x_lengths (unused by reference)
    const float* gamma = (const float*)d_in[2];
    const float* beta  = (const float*)d_in[3];
    const float* w_in  = (const float*)d_in[4];
    const float* b_in  = (const float*)d_in[5];
    const float* w_out = (const float*)d_in[6];
    const float* b_out = (const float*)d_in[7];
    float* out = (float*)d_out;

    char* ws = (char*)d_ws;
    bf16* cw_in  = (bf16*)ws;                   // 786432 elems (1.5 MB)
    bf16* cw_out = cw_in + 786432;              // 262144 (0.5 MB)
    bf16* xn     = (bf16*)(ws + (4u << 20));    // 8 MB
    bf16* qkv    = (bf16*)(ws + (12u << 20));   // 24 MB
    bf16* ctx    = xn;                          // xn dead after QKV GEMM

    prep_kernel<<<2560, 256, 0, stream>>>(x, gamma, beta, w_in, w_out, xn, cw_in, cw_out);
    gemm_bt<128, bf16><<<dim3(12, 64), 256, 0, stream>>>(xn, cw_in, b_in, qkv, 1536, 512);
    attn_kernel<<<dim3(16, 64), 256, 0, stream>>>(qkv, ctx);
    gemm_bt<64, float><<<dim3(4, 128), 256, 0, stream>>>(ctx, cw_out, b_out, out, 512, 512);
}